// Round 3
// baseline (127.040 us; speedup 1.0000x reference)
//
#include <hip/hip_runtime.h>

// LinearMemoryBackend: y_t = M_t q_t, M_t = sum_{s<=t} v_s k_s^T
// Chunked (C=64), MFMA bf16 version.
//  k1: W[bid][d][e] = S_c^T = sum_t v[t,d] k[t,e]   (K,V hi/lo bf16 split, fp32 out)
//  k2: exclusive prefix over chunks (fp32; 65536 scalar column-scans, all CUs)
//  k3: y = (QK^T masked)V + Q*M   (M hi/lo bf16 split)

#define B_   2
#define T_   4096
#define H_   8
#define D_   64
#define CH   64
#define NC   (T_ / CH)
#define BH   (B_ * H_)
#define SROW (H_ * D_)
#define SB   (T_ * H_ * D_)

typedef __attribute__((ext_vector_type(4))) float f32x4;
typedef __attribute__((ext_vector_type(8))) short bf16x8;

__device__ inline unsigned short f2bf(float f) {
  unsigned int u = __builtin_bit_cast(unsigned int, f);
  unsigned int r = (u + 0x7FFFu + ((u >> 16) & 1u)) >> 16;
  return (unsigned short)r;
}
__device__ inline float bf2f(unsigned short b) {
  unsigned int u = ((unsigned int)b) << 16;
  return __builtin_bit_cast(float, u);
}
__device__ inline void st4bf(unsigned short* p, float a, float b, float c, float d) {
  union { uint2 u; unsigned short s[4]; } x;
  x.s[0] = f2bf(a); x.s[1] = f2bf(b); x.s[2] = f2bf(c); x.s[3] = f2bf(d);
  *(uint2*)p = x.u;
}
__device__ inline bf16x8 ld128(const unsigned short* p) {
  union { uint4 u; bf16x8 v; } x;
  x.u = *(const uint4*)p;
  return x.v;
}

// fragment slot orderings (lane l: m = l&15, q = l>>4)
//  row-access operands (A rows / B^T rows loaded as 8 consecutive k): slot_A = m*4+q
//  transpose-staged operands (k = time contiguous):                   slot_V = (m&3)*16 + q*4 + (m>>2)

// ---------------- kernel 1: chunk outer-product sums via MFMA ----------------
__global__ __launch_bounds__(256) void k_chunksum(const float* __restrict__ kp,
                                                  const float* __restrict__ vp,
                                                  float* __restrict__ W) {
  const int bid = blockIdx.x;
  const int c   = bid % NC;
  const int bh  = bid / NC;
  const int b   = bh / H_, h = bh % H_;
  const size_t base = (size_t)b * SB + (size_t)h * D_ + (size_t)(c * CH) * SROW;

  __shared__ __align__(16) unsigned short KH[4096], KL[4096], VH[4096], VL[4096];

  const int tid = threadIdx.x;
  const int l = tid & 63, w = tid >> 6;
  const int mlan = l & 15, qlan = l >> 4;

  // stage K,V transposed (4x4 register transpose), hi/lo split
  {
    const int t0 = (tid >> 4) * 4;
    const int m0 = tid & 15;
    const int qs = (t0 >> 3) & 3, kbs = t0 >> 5, j0 = t0 & 4;
    float4 kr[4], vr[4];
#pragma unroll
    for (int i = 0; i < 4; ++i) {
      const size_t g = base + (size_t)(t0 + i) * SROW + 4 * m0;
      kr[i] = *(const float4*)(kp + g);
      vr[i] = *(const float4*)(vp + g);
    }
#pragma unroll
    for (int r = 0; r < 4; ++r) {
      const int d = 4 * m0 + r;
      const int slot = r * 16 + qs * 4 + (m0 & 3);
      const int addr = (((d >> 4) * 2 + kbs) * 64 + slot) * 8 + j0;
      float ke[4] = { ((const float*)&kr[0])[r], ((const float*)&kr[1])[r],
                      ((const float*)&kr[2])[r], ((const float*)&kr[3])[r] };
      float ve[4] = { ((const float*)&vr[0])[r], ((const float*)&vr[1])[r],
                      ((const float*)&vr[2])[r], ((const float*)&vr[3])[r] };
      float kh[4], vh[4];
#pragma unroll
      for (int i = 0; i < 4; ++i) { kh[i] = bf2f(f2bf(ke[i])); vh[i] = bf2f(f2bf(ve[i])); }
      st4bf(KH + addr, kh[0], kh[1], kh[2], kh[3]);
      st4bf(KL + addr, ke[0] - kh[0], ke[1] - kh[1], ke[2] - kh[2], ke[3] - kh[3]);
      st4bf(VH + addr, vh[0], vh[1], vh[2], vh[3]);
      st4bf(VL + addr, ve[0] - vh[0], ve[1] - vh[1], ve[2] - vh[2], ve[3] - vh[3]);
    }
  }
  __syncthreads();

  const int rslot = ((mlan & 3) << 4) + (qlan << 2) + (mlan >> 2);

  bf16x8 avh[2], avl[2];
#pragma unroll
  for (int kb = 0; kb < 2; ++kb) {
    avh[kb] = ld128(VH + ((w * 2 + kb) * 64 + rslot) * 8);
    avl[kb] = ld128(VL + ((w * 2 + kb) * 64 + rslot) * 8);
  }
  float* Wc = W + (size_t)bid * (D_ * D_);
#pragma unroll
  for (int te = 0; te < 4; ++te) {
    f32x4 acc = {0.f, 0.f, 0.f, 0.f};
#pragma unroll
    for (int kb = 0; kb < 2; ++kb) {
      bf16x8 bkh = ld128(KH + ((te * 2 + kb) * 64 + rslot) * 8);
      bf16x8 bkl = ld128(KL + ((te * 2 + kb) * 64 + rslot) * 8);
      acc = __builtin_amdgcn_mfma_f32_16x16x32_bf16(avh[kb], bkh, acc, 0, 0, 0);
      acc = __builtin_amdgcn_mfma_f32_16x16x32_bf16(avl[kb], bkh, acc, 0, 0, 0);
      acc = __builtin_amdgcn_mfma_f32_16x16x32_bf16(avh[kb], bkl, acc, 0, 0, 0);
    }
#pragma unroll
    for (int r = 0; r < 4; ++r)
      Wc[(16 * w + 4 * qlan + r) * D_ + 16 * te + mlan] = acc[r];
  }
}

// ---------------- kernel 2: exclusive prefix over chunks ----------------
// One scalar column per thread: 65536 threads = 256 blocks -> all CUs active.
// 16-deep load batches keep 16 loads in flight ahead of the dependent
// store/accumulate chain.
__global__ __launch_bounds__(256) void k_prefix(float* __restrict__ W) {
  const int g = blockIdx.x * 256 + threadIdx.x;           // 0..65535
  float* base = W + (size_t)(g >> 12) * (NC * D_ * D_) + (g & 4095);
  float run = 0.f;
#pragma unroll
  for (int grp = 0; grp < 4; ++grp) {
    float v[16];
#pragma unroll
    for (int i = 0; i < 16; ++i)
      v[i] = base[(size_t)(grp * 16 + i) * (D_ * D_)];
#pragma unroll
    for (int i = 0; i < 16; ++i) {
      base[(size_t)(grp * 16 + i) * (D_ * D_)] = run;
      run += v[i];
    }
  }
}

// ---------------- kernel 3: y = (QK^T masked)V + Q*M via MFMA ----------------
__global__ __launch_bounds__(256) void k_output(const float* __restrict__ qp,
                                                const float* __restrict__ kp,
                                                const float* __restrict__ vp,
                                                const float* __restrict__ W,
                                                float* __restrict__ yp) {
  const int bid = blockIdx.x;
  const int c   = bid % NC;
  const int bh  = bid / NC;
  const int b   = bh / H_, h = bh % H_;
  const size_t base = (size_t)b * SB + (size_t)h * D_ + (size_t)(c * CH) * SROW;

  __shared__ __align__(16) unsigned short QF[4096], KF[4096], VF[4096],
                                          MH[4096], ML[4096], PS[64 * 72];

  const int tid = threadIdx.x;
  const int l = tid & 63, w = tid >> 6;
  const int mlan = l & 15, qlan = l >> 4;

  // --- stage Q, K (row-access A/B form) and M (hi/lo) ---
#pragma unroll
  for (int it = 0; it < 4; ++it) {
    const int f = tid + it * 256;
    const int t = f >> 4, m0 = f & 15;
    const int kb = m0 >> 3, q = (m0 & 7) >> 1, j0 = (m0 & 1) * 4;
    const int addr = (((t >> 4) * 2 + kb) * 64 + ((t & 15) * 4 + q)) * 8 + j0;
    const size_t g = base + (size_t)t * SROW + 4 * m0;
    float4 qv = *(const float4*)(qp + g);
    float4 kv = *(const float4*)(kp + g);
    st4bf(QF + addr, qv.x, qv.y, qv.z, qv.w);
    st4bf(KF + addr, kv.x, kv.y, kv.z, kv.w);
    float4 mv = *(const float4*)(W + (size_t)bid * (D_ * D_) + t * D_ + 4 * m0);
    float mh[4] = { bf2f(f2bf(mv.x)), bf2f(f2bf(mv.y)), bf2f(f2bf(mv.z)), bf2f(f2bf(mv.w)) };
    st4bf(MH + addr, mh[0], mh[1], mh[2], mh[3]);
    st4bf(ML + addr, mv.x - mh[0], mv.y - mh[1], mv.z - mh[2], mv.w - mh[3]);
  }
  // --- stage V transposed ---
  {
    const int s0 = (tid >> 4) * 4;
    const int m0 = tid & 15;
    const int qs = (s0 >> 3) & 3, kbs = s0 >> 5, j0 = s0 & 4;
    float4 vr[4];
#pragma unroll
    for (int i = 0; i < 4; ++i)
      vr[i] = *(const float4*)(vp + base + (size_t)(s0 + i) * SROW + 4 * m0);
#pragma unroll
    for (int r = 0; r < 4; ++r) {
      const int d = 4 * m0 + r;
      const int slot = r * 16 + qs * 4 + (m0 & 3);
      const int addr = (((d >> 4) * 2 + kbs) * 64 + slot) * 8 + j0;
      st4bf(VF + addr, ((const float*)&vr[0])[r], ((const float*)&vr[1])[r],
                       ((const float*)&vr[2])[r], ((const float*)&vr[3])[r]);
    }
  }
  __syncthreads();

  // --- Q A-frags ---
  bf16x8 aq[2];
#pragma unroll
  for (int kb = 0; kb < 2; ++kb)
    aq[kb] = ld128(QF + ((w * 2 + kb) * 64 + (mlan * 4 + qlan)) * 8);

  // --- matmul1: P = Q K^T (causal tiles only) ---
  f32x4 accP[4];
#pragma unroll
  for (int ts = 0; ts < 4; ++ts) accP[ts] = (f32x4){0.f, 0.f, 0.f, 0.f};
#pragma unroll
  for (int ts = 0; ts < 4; ++ts) {
    if (ts <= w) {
#pragma unroll
      for (int kb = 0; kb < 2; ++kb) {
        bf16x8 bk = ld128(KF + ((ts * 2 + kb) * 64 + (mlan * 4 + qlan)) * 8);
        accP[ts] = __builtin_amdgcn_mfma_f32_16x16x32_bf16(aq[kb], bk, accP[ts], 0, 0, 0);
      }
    }
  }
  // mask diagonal tile (keep s<=t)
#pragma unroll
  for (int ts = 0; ts < 4; ++ts) {
    if (ts == w) {
#pragma unroll
      for (int r = 0; r < 4; ++r)
        if (mlan > qlan * 4 + r) accP[ts][r] = 0.f;
    }
  }
  // write P strip (rows 16w..16w+15) to LDS row-major (stride 72)
#pragma unroll
  for (int ts = 0; ts < 4; ++ts)
#pragma unroll
    for (int r = 0; r < 4; ++r)
      PS[(16 * w + 4 * qlan + r) * 72 + 16 * ts + mlan] = f2bf(accP[ts][r]);

  // --- P A-frags (same-wave LDS round-trip; strip is wave-private) ---
  bf16x8 ap[2];
#pragma unroll
  for (int sb = 0; sb < 2; ++sb)
    ap[sb] = ld128(PS + (16 * w + mlan) * 72 + 32 * sb + 8 * qlan);

  const int rslot = ((mlan & 3) << 4) + (qlan << 2) + (mlan >> 2);

  f32x4 accY[4];
#pragma unroll
  for (int td = 0; td < 4; ++td) accY[td] = (f32x4){0.f, 0.f, 0.f, 0.f};

  // --- matmul2: Y += P V ---
#pragma unroll
  for (int td = 0; td < 4; ++td)
#pragma unroll
    for (int sb = 0; sb < 2; ++sb) {
      bf16x8 bv = ld128(VF + ((td * 2 + sb) * 64 + rslot) * 8);
      accY[td] = __builtin_amdgcn_mfma_f32_16x16x32_bf16(ap[sb], bv, accY[td], 0, 0, 0);
    }
  // --- matmul3: Y += Q * (Mhi + Mlo) ---
#pragma unroll
  for (int td = 0; td < 4; ++td)
#pragma unroll
    for (int kb = 0; kb < 2; ++kb) {
      bf16x8 bmh = ld128(MH + ((td * 2 + kb) * 64 + (mlan * 4 + qlan)) * 8);
      accY[td] = __builtin_amdgcn_mfma_f32_16x16x32_bf16(aq[kb], bmh, accY[td], 0, 0, 0);
      bf16x8 bml = ld128(ML + ((td * 2 + kb) * 64 + (mlan * 4 + qlan)) * 8);
      accY[td] = __builtin_amdgcn_mfma_f32_16x16x32_bf16(aq[kb], bml, accY[td], 0, 0, 0);
    }

  // --- store Y ---
#pragma unroll
  for (int td = 0; td < 4; ++td)
#pragma unroll
    for (int r = 0; r < 4; ++r)
      yp[base + (size_t)(16 * w + 4 * qlan + r) * SROW + 16 * td + mlan] = accY[td][r];
}

extern "C" void kernel_launch(void* const* d_in, const int* in_sizes, int n_in,
                              void* d_out, int out_size, void* d_ws, size_t ws_size,
                              hipStream_t stream) {
  const float* q = (const float*)d_in[0];
  const float* k = (const float*)d_in[1];
  const float* v = (const float*)d_in[2];
  float* y = (float*)d_out;
  float* W = (float*)d_ws;  // BH*NC*D*D*4 B = 16.78 MB

  k_chunksum<<<BH * NC, 256, 0, stream>>>(k, v, W);
  k_prefix  <<<BH * 64, 256, 0, stream>>>(W);
  k_output  <<<BH * NC, 256, 0, stream>>>(q, k, v, W, y);
}

// Round 4
// 111.600 us; speedup vs baseline: 1.1384x; 1.1384x over previous
//
#include <hip/hip_runtime.h>

// LinearMemoryBackend: y_t = M_t q_t, M_t = sum_{s<=t} v_s k_s^T
// Chunked (C=64), MFMA bf16 version.
//  k1: W[bid][d][e] = S_c^T = sum_t v[t,d] k[t,e]   (K,V hi/lo bf16 split, fp32 out)
//  k2: exclusive prefix over chunks (fp32; 65536 scalar column-scans = 256 blocks)
//  k3: y = (QK^T masked)V + Q*M   (M hi/lo bf16 split)

#define B_   2
#define T_   4096
#define H_   8
#define D_   64
#define CH   64
#define NC   (T_ / CH)
#define BH   (B_ * H_)
#define SROW (H_ * D_)
#define SB   (T_ * H_ * D_)

typedef __attribute__((ext_vector_type(4))) float f32x4;
typedef __attribute__((ext_vector_type(8))) short bf16x8;

__device__ inline unsigned short f2bf(float f) {
  unsigned int u = __builtin_bit_cast(unsigned int, f);
  unsigned int r = (u + 0x7FFFu + ((u >> 16) & 1u)) >> 16;
  return (unsigned short)r;
}
__device__ inline float bf2f(unsigned short b) {
  unsigned int u = ((unsigned int)b) << 16;
  return __builtin_bit_cast(float, u);
}
__device__ inline void st4bf(unsigned short* p, float a, float b, float c, float d) {
  union { uint2 u; unsigned short s[4]; } x;
  x.s[0] = f2bf(a); x.s[1] = f2bf(b); x.s[2] = f2bf(c); x.s[3] = f2bf(d);
  *(uint2*)p = x.u;
}
__device__ inline bf16x8 ld128(const unsigned short* p) {
  union { uint4 u; bf16x8 v; } x;
  x.u = *(const uint4*)p;
  return x.v;
}

// fragment slot orderings (lane l: m = l&15, q = l>>4)
//  row-access operands (A rows / B^T rows loaded as 8 consecutive k): slot_A = m*4+q
//  transpose-staged operands (k = time contiguous):                   slot_V = (m&3)*16 + q*4 + (m>>2)

// ---------------- kernel 1: chunk outer-product sums via MFMA ----------------
__global__ __launch_bounds__(256) void k_chunksum(const float* __restrict__ kp,
                                                  const float* __restrict__ vp,
                                                  float* __restrict__ W) {
  const int bid = blockIdx.x;
  const int c   = bid % NC;
  const int bh  = bid / NC;
  const int b   = bh / H_, h = bh % H_;
  const size_t base = (size_t)b * SB + (size_t)h * D_ + (size_t)(c * CH) * SROW;

  __shared__ __align__(16) unsigned short KH[4096], KL[4096], VH[4096], VL[4096];

  const int tid = threadIdx.x;
  const int l = tid & 63, w = tid >> 6;
  const int mlan = l & 15, qlan = l >> 4;

  // stage K,V transposed (4x4 register transpose), hi/lo split
  {
    const int t0 = (tid >> 4) * 4;
    const int m0 = tid & 15;
    const int qs = (t0 >> 3) & 3, kbs = t0 >> 5, j0 = t0 & 4;
    float4 kr[4], vr[4];
#pragma unroll
    for (int i = 0; i < 4; ++i) {
      const size_t g = base + (size_t)(t0 + i) * SROW + 4 * m0;
      kr[i] = *(const float4*)(kp + g);
      vr[i] = *(const float4*)(vp + g);
    }
#pragma unroll
    for (int r = 0; r < 4; ++r) {
      const int d = 4 * m0 + r;
      const int slot = r * 16 + qs * 4 + (m0 & 3);
      const int addr = (((d >> 4) * 2 + kbs) * 64 + slot) * 8 + j0;
      float ke[4] = { ((const float*)&kr[0])[r], ((const float*)&kr[1])[r],
                      ((const float*)&kr[2])[r], ((const float*)&kr[3])[r] };
      float ve[4] = { ((const float*)&vr[0])[r], ((const float*)&vr[1])[r],
                      ((const float*)&vr[2])[r], ((const float*)&vr[3])[r] };
      float kh[4], vh[4];
#pragma unroll
      for (int i = 0; i < 4; ++i) { kh[i] = bf2f(f2bf(ke[i])); vh[i] = bf2f(f2bf(ve[i])); }
      st4bf(KH + addr, kh[0], kh[1], kh[2], kh[3]);
      st4bf(KL + addr, ke[0] - kh[0], ke[1] - kh[1], ke[2] - kh[2], ke[3] - kh[3]);
      st4bf(VH + addr, vh[0], vh[1], vh[2], vh[3]);
      st4bf(VL + addr, ve[0] - vh[0], ve[1] - vh[1], ve[2] - vh[2], ve[3] - vh[3]);
    }
  }
  __syncthreads();

  const int rslot = ((mlan & 3) << 4) + (qlan << 2) + (mlan >> 2);

  bf16x8 avh[2], avl[2];
#pragma unroll
  for (int kb = 0; kb < 2; ++kb) {
    avh[kb] = ld128(VH + ((w * 2 + kb) * 64 + rslot) * 8);
    avl[kb] = ld128(VL + ((w * 2 + kb) * 64 + rslot) * 8);
  }
  float* Wc = W + (size_t)bid * (D_ * D_);
#pragma unroll
  for (int te = 0; te < 4; ++te) {
    f32x4 acc = {0.f, 0.f, 0.f, 0.f};
#pragma unroll
    for (int kb = 0; kb < 2; ++kb) {
      bf16x8 bkh = ld128(KH + ((te * 2 + kb) * 64 + rslot) * 8);
      bf16x8 bkl = ld128(KL + ((te * 2 + kb) * 64 + rslot) * 8);
      acc = __builtin_amdgcn_mfma_f32_16x16x32_bf16(avh[kb], bkh, acc, 0, 0, 0);
      acc = __builtin_amdgcn_mfma_f32_16x16x32_bf16(avl[kb], bkh, acc, 0, 0, 0);
      acc = __builtin_amdgcn_mfma_f32_16x16x32_bf16(avh[kb], bkl, acc, 0, 0, 0);
    }
#pragma unroll
    for (int r = 0; r < 4; ++r)
      Wc[(16 * w + 4 * qlan + r) * D_ + 16 * te + mlan] = acc[r];
  }
}

// ---------------- kernel 2: exclusive prefix over chunks ----------------
// One scalar column per thread: 65536 threads = 256 blocks (all CUs).
// 16-deep load batches keep 16 loads in flight ahead of the dependent
// store/accumulate chain.
__global__ __launch_bounds__(256) void k_prefix(float* __restrict__ W) {
  const int g = blockIdx.x * 256 + threadIdx.x;           // 0..65535
  float* base = W + (size_t)(g >> 12) * (NC * D_ * D_) + (g & 4095);
  float run = 0.f;
#pragma unroll
  for (int grp = 0; grp < 4; ++grp) {
    float v[16];
#pragma unroll
    for (int i = 0; i < 16; ++i)
      v[i] = base[(size_t)(grp * 16 + i) * (D_ * D_)];
#pragma unroll
    for (int i = 0; i < 16; ++i) {
      base[(size_t)(grp * 16 + i) * (D_ * D_)] = run;
      run += v[i];
    }
  }
}

// ---------------- kernel 3: y = (QK^T masked)V + Q*M via MFMA ----------------
__global__ __launch_bounds__(256) void k_output(const float* __restrict__ qp,
                                                const float* __restrict__ kp,
                                                const float* __restrict__ vp,
                                                const float* __restrict__ W,
                                                float* __restrict__ yp) {
  const int bid = blockIdx.x;
  const int c   = bid % NC;
  const int bh  = bid / NC;
  const int b   = bh / H_, h = bh % H_;
  const size_t base = (size_t)b * SB + (size_t)h * D_ + (size_t)(c * CH) * SROW;

  __shared__ __align__(16) unsigned short QF[4096], KF[4096], VF[4096],
                                          MH[4096], ML[4096], PS[64 * 72];

  const int tid = threadIdx.x;
  const int l = tid & 63, w = tid >> 6;
  const int mlan = l & 15, qlan = l >> 4;

  // --- stage Q, K (row-access A/B form) and M (hi/lo) ---
#pragma unroll
  for (int it = 0; it < 4; ++it) {
    const int f = tid + it * 256;
    const int t = f >> 4, m0 = f & 15;
    const int kb = m0 >> 3, q = (m0 & 7) >> 1, j0 = (m0 & 1) * 4;
    const int addr = (((t >> 4) * 2 + kb) * 64 + ((t & 15) * 4 + q)) * 8 + j0;
    const size_t g = base + (size_t)t * SROW + 4 * m0;
    float4 qv = *(const float4*)(qp + g);
    float4 kv = *(const float4*)(kp + g);
    st4bf(QF + addr, qv.x, qv.y, qv.z, qv.w);
    st4bf(KF + addr, kv.x, kv.y, kv.z, kv.w);
    float4 mv = *(const float4*)(W + (size_t)bid * (D_ * D_) + t * D_ + 4 * m0);
    float mh[4] = { bf2f(f2bf(mv.x)), bf2f(f2bf(mv.y)), bf2f(f2bf(mv.z)), bf2f(f2bf(mv.w)) };
    st4bf(MH + addr, mh[0], mh[1], mh[2], mh[3]);
    st4bf(ML + addr, mv.x - mh[0], mv.y - mh[1], mv.z - mh[2], mv.w - mh[3]);
  }
  // --- stage V transposed ---
  {
    const int s0 = (tid >> 4) * 4;
    const int m0 = tid & 15;
    const int qs = (s0 >> 3) & 3, kbs = s0 >> 5, j0 = s0 & 4;
    float4 vr[4];
#pragma unroll
    for (int i = 0; i < 4; ++i)
      vr[i] = *(const float4*)(vp + base + (size_t)(s0 + i) * SROW + 4 * m0);
#pragma unroll
    for (int r = 0; r < 4; ++r) {
      const int d = 4 * m0 + r;
      const int slot = r * 16 + qs * 4 + (m0 & 3);
      const int addr = (((d >> 4) * 2 + kbs) * 64 + slot) * 8 + j0;
      st4bf(VF + addr, ((const float*)&vr[0])[r], ((const float*)&vr[1])[r],
                       ((const float*)&vr[2])[r], ((const float*)&vr[3])[r]);
    }
  }
  __syncthreads();

  // --- Q A-frags ---
  bf16x8 aq[2];
#pragma unroll
  for (int kb = 0; kb < 2; ++kb)
    aq[kb] = ld128(QF + ((w * 2 + kb) * 64 + (mlan * 4 + qlan)) * 8);

  // --- matmul1: P = Q K^T (causal tiles only) ---
  f32x4 accP[4];
#pragma unroll
  for (int ts = 0; ts < 4; ++ts) accP[ts] = (f32x4){0.f, 0.f, 0.f, 0.f};
#pragma unroll
  for (int ts = 0; ts < 4; ++ts) {
    if (ts <= w) {
#pragma unroll
      for (int kb = 0; kb < 2; ++kb) {
        bf16x8 bk = ld128(KF + ((ts * 2 + kb) * 64 + (mlan * 4 + qlan)) * 8);
        accP[ts] = __builtin_amdgcn_mfma_f32_16x16x32_bf16(aq[kb], bk, accP[ts], 0, 0, 0);
      }
    }
  }
  // mask diagonal tile (keep s<=t)
#pragma unroll
  for (int ts = 0; ts < 4; ++ts) {
    if (ts == w) {
#pragma unroll
      for (int r = 0; r < 4; ++r)
        if (mlan > qlan * 4 + r) accP[ts][r] = 0.f;
    }
  }
  // write P strip (rows 16w..16w+15) to LDS row-major (stride 72)
#pragma unroll
  for (int ts = 0; ts < 4; ++ts)
#pragma unroll
    for (int r = 0; r < 4; ++r)
      PS[(16 * w + 4 * qlan + r) * 72 + 16 * ts + mlan] = f2bf(accP[ts][r]);

  // --- P A-frags (same-wave LDS round-trip; strip is wave-private) ---
  bf16x8 ap[2];
#pragma unroll
  for (int sb = 0; sb < 2; ++sb)
    ap[sb] = ld128(PS + (16 * w + mlan) * 72 + 32 * sb + 8 * qlan);

  const int rslot = ((mlan & 3) << 4) + (qlan << 2) + (mlan >> 2);

  f32x4 accY[4];
#pragma unroll
  for (int td = 0; td < 4; ++td) accY[td] = (f32x4){0.f, 0.f, 0.f, 0.f};

  // --- matmul2: Y += P V ---
#pragma unroll
  for (int td = 0; td < 4; ++td)
#pragma unroll
    for (int sb = 0; sb < 2; ++sb) {
      bf16x8 bv = ld128(VF + ((td * 2 + sb) * 64 + rslot) * 8);
      accY[td] = __builtin_amdgcn_mfma_f32_16x16x32_bf16(ap[sb], bv, accY[td], 0, 0, 0);
    }
  // --- matmul3: Y += Q * (Mhi + Mlo) ---
#pragma unroll
  for (int td = 0; td < 4; ++td)
#pragma unroll
    for (int kb = 0; kb < 2; ++kb) {
      bf16x8 bmh = ld128(MH + ((td * 2 + kb) * 64 + (mlan * 4 + qlan)) * 8);
      accY[td] = __builtin_amdgcn_mfma_f32_16x16x32_bf16(aq[kb], bmh, accY[td], 0, 0, 0);
      bf16x8 bml = ld128(ML + ((td * 2 + kb) * 64 + (mlan * 4 + qlan)) * 8);
      accY[td] = __builtin_amdgcn_mfma_f32_16x16x32_bf16(aq[kb], bml, accY[td], 0, 0, 0);
    }

  // --- store Y ---
#pragma unroll
  for (int td = 0; td < 4; ++td)
#pragma unroll
    for (int r = 0; r < 4; ++r)
      yp[base + (size_t)(16 * w + 4 * qlan + r) * SROW + 16 * td + mlan] = accY[td][r];
}

extern "C" void kernel_launch(void* const* d_in, const int* in_sizes, int n_in,
                              void* d_out, int out_size, void* d_ws, size_t ws_size,
                              hipStream_t stream) {
  const float* q = (const float*)d_in[0];
  const float* k = (const float*)d_in[1];
  const float* v = (const float*)d_in[2];
  float* y = (float*)d_out;
  float* W = (float*)d_ws;  // BH*NC*D*D*4 B = 16.78 MB

  k_chunksum<<<BH * NC, 256, 0, stream>>>(k, v, W);
  k_prefix  <<<256, 256, 0, stream>>>(W);   // 65536 threads = one per column (16 bh x 4096)
  k_output  <<<BH * NC, 256, 0, stream>>>(q, k, v, W, y);
}